// Round 7
// baseline (57.858 us; speedup 1.0000x reference)
//
#include <hip/hip_runtime.h>
#include <hip/hip_bf16.h>

// DivEncLayer via MFMA, R7. per (b,q): z = W1^T x + b1; out = sum_h w2p*elu(z) + b2p.
// B=32768, Q=128, S=8, H=32, f32 I/O; bf16 MFMA dense1, f32 epilogue.
//
// R6 -> R7 (counter-driven): VALUBusy 37.6% at Occupancy 35% (4096 waves = 16/CU cap) =
// latency-bound from wave starvation, not issue count. Fix: 128 b-rows/block ->
// 1024 blocks = 32 waves/CU; VGPR must stay <=64 for 8 waves/SIMD (R6 measured 56).
//  - both subs' x issued at qg head (2 loads deep in flight)
//  - single barrier: slab[128][36] (stride 36 floats = 144B, 16B-aligned float4 reads)
//  - acc init = 0.5*b2p (b2p materializes via the half-combine shuffle add)
//  - qg loop rolled (pointer increments) to keep regalloc at the 8-wave cliff

#define QN 128
#define SN 8
#define HN 32
#define XROW 1024
#define BN_EPS 1e-3f

typedef short bf16x8 __attribute__((ext_vector_type(8)));
typedef float f32x16 __attribute__((ext_vector_type(16)));
typedef unsigned int u32;

#define WS_A_BYTES (QN * 64 * 16)                 // A1pack[q][lane] 16B (hi lanes zero)
#define WS_C_OFF   WS_A_BYTES
#define WS_C_BYTES (QN * 32 * 4)                  // c_init[q][half*16+r] = b1 (f32, reg order)
#define WS_W_OFF   (WS_C_OFF + WS_C_BYTES)
#define WS_W_BYTES (QN * 32 * 4)                  // w2p[q][half*16+r]   (f32, reg order)
#define WS_B2_OFF  (WS_W_OFF + WS_W_BYTES)        // b2p[q]

static __device__ __forceinline__ u32 pkbf(float lo, float hi) {
    union { __hip_bfloat162 h2; u32 u; } c;
    c.h2 = __float22bfloat162_rn(float2{lo, hi});
    return c.u;
}

__global__ void divenc_prep(const float* __restrict__ W1, const float* __restrict__ b1,
                            const float* __restrict__ gamma_, const float* __restrict__ beta_,
                            const float* __restrict__ mmean, const float* __restrict__ mvar,
                            const float* __restrict__ W2, const float* __restrict__ b2,
                            unsigned char* __restrict__ ws)
{
    const int q = blockIdx.x;        // 0..127
    const int m = threadIdx.x;       // 0..63

    u32 d0 = 0, d1 = 0, d2 = 0, d3 = 0;
    if (m < 32) {                    // A[m][k] = W1[q][k][m], k pairs per dword
        d0 = pkbf(W1[(q*SN + 0)*HN + m], W1[(q*SN + 1)*HN + m]);
        d1 = pkbf(W1[(q*SN + 2)*HN + m], W1[(q*SN + 3)*HN + m]);
        d2 = pkbf(W1[(q*SN + 4)*HN + m], W1[(q*SN + 5)*HN + m]);
        d3 = pkbf(W1[(q*SN + 6)*HN + m], W1[(q*SN + 7)*HN + m]);
    }
    ((uint4*)ws)[q*64 + m] = uint4{d0, d1, d2, d3};

    float* wsC  = (float*)(ws + WS_C_OFF);
    float* wsW  = (float*)(ws + WS_W_OFF);
    float* wsB2 = (float*)(ws + WS_B2_OFF);
    if (m < 32) {                    // D-reg order: h = (r&3) + 8*(r>>2) + 4*half
        const int half = m >> 4, r = m & 15;
        const int h = (r & 3) + 8*(r >> 2) + 4*half;
        wsC[q*32 + m] = b1[q*HN + h];
        float inv = gamma_[q*HN+h] * rsqrtf(mvar[q*HN+h] + BN_EPS);
        wsW[q*32 + m] = inv * W2[q*HN + h];
    }
    if (m == 0) {
        float acc = b2[q];
        for (int h = 0; h < HN; ++h) {
            float inv = gamma_[q*HN+h] * rsqrtf(mvar[q*HN+h] + BN_EPS);
            acc += (beta_[q*HN+h] - mmean[q*HN+h]*inv) * W2[q*HN+h];
        }
        wsB2[q] = acc;
    }
}

__global__ __launch_bounds__(512, 6)
void divenc_mfma(const float* __restrict__ x, const unsigned char* __restrict__ ws,
                 float* __restrict__ out)
{
    const int lane = threadIdx.x & 63;
    const int wv   = threadIdx.x >> 6;   // 0..7
    const int half = lane >> 5;
    const int bl   = lane & 31;
    const int b0   = blockIdx.x * 128;
    const int q0   = blockIdx.y * 32;

    __shared__ float slab[128][36];      // 18.4 KiB; written once per loc, read after barrier

    const uint4* wsA  = (const uint4*)ws + (size_t)(q0 + wv) * 64;
    const float* wsC  = (const float*)(ws + WS_C_OFF) + (q0 + wv) * 32 + half * 16;
    const float* wsW  = (const float*)(ws + WS_W_OFF) + (q0 + wv) * 32 + half * 16;
    const float* wsB2 = (const float*)(ws + WS_B2_OFF) + (q0 + wv);
    const float* xq   = x + (size_t)(b0 + lane) * XROW + (q0 + wv) * SN;

    #pragma unroll 1
    for (int qg = 0; qg < 4; ++qg) {
        // x for both 64-row subs first (deepest latency, 2 rows in flight per lane)
        float4 xa0 = *(const float4*)(xq);
        float4 xc0 = *(const float4*)(xq + 4);
        float4 xa1 = *(const float4*)(xq + 64 * XROW);
        float4 xc1 = *(const float4*)(xq + 64 * XROW + 4);

        union { uint4 u; bf16x8 v; } A1, A2;
        A1.u = wsA[lane];                 // W1 in lanes<32 (k0-7), zeros above
        A2.u = wsA[lane ^ 32];            // same bytes -> W1 in k8-15 slots

        f32x16 cini;
        float w2r[16];
        #pragma unroll
        for (int r = 0; r < 16; ++r) { cini[r] = wsC[r]; w2r[r] = wsW[r]; }
        const float hb2 = 0.5f * wsB2[0];

        // ---- sub 0: b-rows b0 .. b0+63 ----
        {
            union { uint4 u; bf16x8 v; } B;
            B.u = uint4{ pkbf(xa0.x, xa0.y), pkbf(xa0.z, xa0.w),
                         pkbf(xc0.x, xc0.y), pkbf(xc0.z, xc0.w) };
            f32x16 D0 = __builtin_amdgcn_mfma_f32_32x32x16_bf16(A1.v, B.v, cini, 0, 0, 0);
            f32x16 D1 = __builtin_amdgcn_mfma_f32_32x32x16_bf16(A2.v, B.v, cini, 0, 0, 0);
            float p0 = hb2, p1 = hb2;
            #pragma unroll
            for (int r = 0; r < 16; ++r) {
                float z0 = D0[r];
                float e0 = __expf(fminf(z0, 0.f)) - 1.f;
                p0 = fmaf(fmaxf(z0, e0), w2r[r], p0);
                float z1 = D1[r];
                float e1 = __expf(fminf(z1, 0.f)) - 1.f;
                p1 = fmaf(fmaxf(z1, e1), w2r[r], p1);
            }
            p0 += __shfl_xor(p0, 32);     // adds other half's 16 h and its hb2
            p1 += __shfl_xor(p1, 32);
            slab[half*32 + bl][qg*8 + wv] = half ? p1 : p0;
        }

        // ---- sub 1: b-rows b0+64 .. b0+127 ----
        {
            union { uint4 u; bf16x8 v; } B;
            B.u = uint4{ pkbf(xa1.x, xa1.y), pkbf(xa1.z, xa1.w),
                         pkbf(xc1.x, xc1.y), pkbf(xc1.z, xc1.w) };
            f32x16 D0 = __builtin_amdgcn_mfma_f32_32x32x16_bf16(A1.v, B.v, cini, 0, 0, 0);
            f32x16 D1 = __builtin_amdgcn_mfma_f32_32x32x16_bf16(A2.v, B.v, cini, 0, 0, 0);
            float p0 = hb2, p1 = hb2;
            #pragma unroll
            for (int r = 0; r < 16; ++r) {
                float z0 = D0[r];
                float e0 = __expf(fminf(z0, 0.f)) - 1.f;
                p0 = fmaf(fmaxf(z0, e0), w2r[r], p0);
                float z1 = D1[r];
                float e1 = __expf(fminf(z1, 0.f)) - 1.f;
                p1 = fmaf(fmaxf(z1, e1), w2r[r], p1);
            }
            p0 += __shfl_xor(p0, 32);
            p1 += __shfl_xor(p1, 32);
            slab[64 + half*32 + bl][qg*8 + wv] = half ? p1 : p0;
        }

        xq  += 64;            // next qg: q += 8 -> x column += 64 floats
        wsA += 8 * 64;
        wsC += 8 * 32;
        wsW += 8 * 32;
        wsB2 += 8;
    }

    __syncthreads();

    // dump: 128 rows x 32 cols; full 128-B lines per 8-lane group
    #pragma unroll
    for (int p = 0; p < 2; ++p) {
        const int row  = (threadIdx.x >> 3) + p * 64;
        const int col4 = (threadIdx.x & 7) * 4;
        float4 vv;
        vv.x = slab[row][col4 + 0];
        vv.y = slab[row][col4 + 1];
        vv.z = slab[row][col4 + 2];
        vv.w = slab[row][col4 + 3];
        *(float4*)(out + (size_t)(b0 + row) * QN + q0 + col4) = vv;
    }
}

extern "C" void kernel_launch(void* const* d_in, const int* in_sizes, int n_in,
                              void* d_out, int out_size, void* d_ws, size_t ws_size,
                              hipStream_t stream) {
    const float* x      = (const float*)d_in[0];
    const float* W1     = (const float*)d_in[1];
    const float* b1     = (const float*)d_in[2];
    const float* gamma_ = (const float*)d_in[3];
    const float* beta_  = (const float*)d_in[4];
    const float* mmean  = (const float*)d_in[5];
    const float* mvar   = (const float*)d_in[6];
    const float* W2     = (const float*)d_in[7];
    const float* b2     = (const float*)d_in[8];
    float* out = (float*)d_out;
    unsigned char* ws = (unsigned char*)d_ws;

    const int Btot = in_sizes[0] / XROW;              // 32768

    divenc_prep<<<QN, 64, 0, stream>>>(W1, b1, gamma_, beta_, mmean, mvar, W2, b2, ws);
    divenc_mfma<<<dim3(Btot / 128, QN / 32), 512, 0, stream>>>(x, ws, out);
}